// Round 8
// baseline (430.443 us; speedup 1.0000x reference)
//
#include <hip/hip_runtime.h>

#define NUMC 14
#define FD 128
#define SPATIAL (16*128*128)      // 262144 per batch = 2^18
#define N_TOTAL (2*SPATIAL)       // 524288
#define NV 50
#define NH 25
#define TC 13
#define QLEN 4096
#define MCH 64                    // negatives per neg-block
#define NCHUNK 32                 // 2048 / MCH
#define NSTR (FD + 4)             // 132: queue row stride in LDS (words)
#define NSUMBLK 2048              // 256 planes x 8 chunks
#define NNEGBLK (TC * NCHUNK)     // 416
#define THRESH_F 0.3f
#define RSTR 33                   // per-thread LDS stride: 2 regions x 16 + 1 pad

typedef float f32x4 __attribute__((ext_vector_type(4)));

// ws offsets in 4-byte units (keep 16B alignment for float4 regions)
#define WS_SEL     0              // int[656]
#define WS_LOSSP   656            // float[13]
#define WS_CNT0    672            // int[1] (pad to 680)
#define WS_NEGPART 680            // float[650*32] = 20800 -> ends 21480
#define WS_ANORM   21480          // float[656] -> ends 22136 (pad 22144)
#define WS_AROWS   22144          // float[650*128] = 83200 -> ends 105344
#define WS_PART    105344         // float[14*2048] = 28672 -> ends 134016
#define WS_LAB8    134016         // uchar[524288] = 131072 words

// ---------------- kernel 1: label prep + anchor select + init ----------------
__global__ __launch_bounds__(256) void k_pre(const int* __restrict__ labels,
        const int* __restrict__ predict, const float* __restrict__ prob,
        unsigned char* __restrict__ lab8, int* __restrict__ sel, int* __restrict__ cnt0) {
    int blk = blockIdx.x;
    int tid = threadIdx.x;
    if (blk < 512) {
        int n = blk * 1024 + tid * 4;
        int4   lb = *(const int4*)(labels + n);
        float4 pv = *(const float4*)(prob + n);
        uchar4 o;
        o.x = pv.x > THRESH_F ? (unsigned char)(lb.x & 15) : (unsigned char)15;
        o.y = pv.y > THRESH_F ? (unsigned char)(lb.y & 15) : (unsigned char)15;
        o.z = pv.z > THRESH_F ? (unsigned char)(lb.z & 15) : (unsigned char)15;
        o.w = pv.w > THRESH_F ? (unsigned char)(lb.w & 15) : (unsigned char)15;
        *(uchar4*)(lab8 + n) = o;
    } else if (blk < 538) {
        if (tid >= 64) return;
        int cat = blk - 512;               // 0..25
        int c = 1 + (cat >> 1);
        bool hard = (cat & 1) == 0;
        int lane = tid;
        int* slot = sel + (c - 1) * NV + (hard ? 0 : NH);
        int found = 0;
        for (int base = 0; base < N_TOTAL && found < NH; base += 64) {
            int n = base + lane;
            bool m = false;
            int pr = predict[n];
            if (pr == c && prob[n] > THRESH_F) {
                int lb = labels[n];
                m = hard ? (lb != c) : (lb == c);
            }
            unsigned long long mask = __ballot(m);
            int rank = __popcll(mask & ((1ull << lane) - 1ull));
            if (m && (found + rank) < NH) slot[found + rank] = n;
            found += __popcll(mask);
        }
        if (lane >= found && lane < NH) slot[lane] = N_TOTAL - 1;  // OOB-gather clamp
    } else {
        if (tid == 0) cnt0[0] = 0;
    }
}

// ---------------- kernel 2: gather anchors (contig arows) + norms ----------------
__global__ __launch_bounds__(128) void k_gather(const float* __restrict__ feats,
        const int* __restrict__ sel, float* __restrict__ arows, float* __restrict__ anorm) {
    __shared__ float red[2];
    int r = blockIdx.x;          // 0..649
    int t = threadIdx.x;         // 0..127 = channel
    int n = sel[r];
    int b = n >> 18, sp = n & (SPATIAL - 1);
    float v = feats[((size_t)(b * FD + t)) * SPATIAL + sp];
    arows[r * FD + t] = v;
    float a = v * v;
    #pragma unroll
    for (int o = 32; o; o >>= 1) a += __shfl_xor(a, o);
    if ((t & 63) == 0) red[t >> 6] = a;
    __syncthreads();
    if (t == 0) anorm[r] = sqrtf(red[0] + red[1]);
}

// ---------------- kernel 3: negatives (blocks < 416) + class sums (rest) ----------------
__global__ __launch_bounds__(256) void k_main(const float* __restrict__ feats,
        const unsigned char* __restrict__ lab8, const float* __restrict__ queue,
        const float* __restrict__ arows, const float* __restrict__ anorm,
        float* __restrict__ part, float* __restrict__ negpart) {
    __shared__ float smem[256 * RSTR + 64];   // 34.0 KB -> 4 blocks/CU
    int tid = threadIdx.x;
    int lane = tid & 63, w = tid >> 6;

    if (blockIdx.x < NNEGBLK) {
        // ---- negatives: exp-sum partials over 64 queue rows ----
        int ci = blockIdx.x >> 5;          // 0..12
        int chunk = blockIdx.x & 31;       // 0..31
        float* n_s  = smem;                // 64*132 = 8448 floats
        float* an_s = smem + 8448;         // 50
        if (tid < NV) an_s[tid] = anorm[ci * NV + tid];
        const float* qp = queue + ((size_t)(ci + 1) * QLEN + (QLEN / 2) + chunk * MCH) * (size_t)FD;
        for (int i = tid; i < MCH * (FD / 4); i += 256) {
            int m = i >> 5, k4 = i & 31;
            ((float4*)(n_s + m * NSTR))[k4] = ((const float4*)qp)[i];
        }
        __syncthreads();
        // per-lane inverse norm of its negative row (row = lane)
        const float4* nrow = (const float4*)(n_s + lane * NSTR);
        float sq = 0.f;
        #pragma unroll
        for (int k = 0; k < FD / 4; ++k) {
            float4 t = nrow[k];
            sq += t.x*t.x + t.y*t.y + t.z*t.z + t.w*t.w;
        }
        float inn = 10.f * rsqrtf(sq);   // 1/TEMP folded in
        float* np = negpart + (size_t)(ci * NV) * NCHUNK + chunk;   // [row][chunk]
        const float4* abase = (const float4*)(arows + (size_t)(ci * NV) * FD);
        for (int v = w; v < NV; v += 4) {
            const float4* a4 = abase + v * (FD / 4);   // wave-uniform -> L1 broadcast
            float dot = 0.f;
            #pragma unroll
            for (int k = 0; k < FD / 4; ++k) {
                float4 x = a4[k], y = nrow[k];
                dot += x.x*y.x + x.y*y.y + x.z*y.z + x.w*y.w;
            }
            float e = __expf(dot * inn / an_s[v]);
            #pragma unroll
            for (int o = 32; o; o >>= 1) e += __shfl_xor(e, o);
            if (lane == 0) np[(size_t)v * NCHUNK] = e;
        }
    } else {
        // ---- per-class feature sums: native ds_add_f32 into private LDS regions ----
        int sb = blockIdx.x - NNEGBLK;      // 0..2047
        int plane = sb >> 3;                // 0..255 = b*128 + ch
        int chunk = sb & 7;
        int b = plane >> 7;
        int r0 = tid * RSTR;
        #pragma unroll
        for (int k = 0; k < RSTR; ++k) smem[r0 + k] = 0.f;   // own region only

        const f32x4* fp4 = (const f32x4*)(feats + (size_t)plane * SPATIAL) + (chunk << 13);
        const uchar4* lp4 = (const uchar4*)(lab8 + (size_t)b * SPATIAL) + (chunk << 13);
        #pragma unroll 4
        for (int i = 0; i < 32; ++i) {
            f32x4  v = fp4[i * 256 + tid];
            uchar4 u = lp4[i * 256 + tid];
            // fire-and-forget ds_add_f32: 1 DS op/elem, no RMW chain, privacy by region
            unsafeAtomicAdd(&smem[r0 +      (u.x & 15)], v.x);
            unsafeAtomicAdd(&smem[r0 + 16 + (u.y & 15)], v.y);
            unsafeAtomicAdd(&smem[r0 +      (u.z & 15)], v.z);
            unsafeAtomicAdd(&smem[r0 + 16 + (u.w & 15)], v.w);
        }
        __syncthreads();

        // fold 2 regions + wave shuffle-reduce -> block partial (coalesced [class][block])
        float* aux = smem + 256 * RSTR;     // 64 floats
        #pragma unroll
        for (int cc = 0; cc < NUMC; ++cc) {
            float t = smem[r0 + cc] + smem[r0 + 16 + cc];
            #pragma unroll
            for (int o = 32; o; o >>= 1) t += __shfl_xor(t, o);
            if (lane == 0) aux[w * 16 + cc] = t;
        }
        __syncthreads();
        if (tid < NUMC)
            part[(size_t)tid * NSUMBLK + sb] =
                aux[tid] + aux[16 + tid] + aux[32 + tid] + aux[48 + tid];
    }
}

// ---------------- kernel 4: per-class loss + deterministic final reduce ----------------
__global__ __launch_bounds__(256) void k_loss(const float* __restrict__ arows,
        const float* __restrict__ anorm, const float* __restrict__ part,
        const float* __restrict__ negpart, float* __restrict__ lossp,
        int* __restrict__ cnt0, float* __restrict__ out) {
    __shared__ float p_s[FD];
    __shared__ float red_s[2];
    __shared__ float lacc[8];
    int tid = threadIdx.x;
    int ci = blockIdx.x, c = ci + 1;
    // class-sum reduce over 16 partials per channel (cnt cancels under l2n)
    if (tid < 128) {
        float s = 0.f;
        #pragma unroll
        for (int b = 0; b < 2; ++b) {
            const float* pp = part + (size_t)c * NSUMBLK + b * 1024 + tid * 8;
            #pragma unroll
            for (int k = 0; k < 8; ++k) s += pp[k];
        }
        p_s[tid] = s;
    }
    __syncthreads();
    if (tid < 128) {
        float q = p_s[tid] * p_s[tid];
        #pragma unroll
        for (int o = 32; o; o >>= 1) q += __shfl_xor(q, o);
        if ((tid & 63) == 0) red_s[tid >> 6] = q;
    }
    __syncthreads();
    float pninv10 = 10.f * rsqrtf(red_s[0] + red_s[1]);   // 1/(||psum|| * TEMP)
    int grp = tid >> 5, l32 = tid & 31;
    float acc = 0.f;
    for (int r = grp; r < NV; r += 8) {
        int ar = ci * NV + r;
        const float4* a4 = (const float4*)(arows + (size_t)ar * FD);
        const float4* p4 = (const float4*)p_s;
        float4 x = a4[l32], y = p4[l32];
        float d = x.x*y.x + x.y*y.y + x.z*y.z + x.w*y.w;
        float ns = negpart[(size_t)ar * NCHUNK + l32];
        #pragma unroll
        for (int o = 16; o; o >>= 1) { d += __shfl_xor(d, o); ns += __shfl_xor(ns, o); }
        if (l32 == 0) {
            float logit = d * pninv10 / anorm[ar];
            acc += -logit + logf(__expf(logit) + ns);
        }
    }
    if (l32 == 0) lacc[grp] = acc;
    __syncthreads();
    if (tid == 0) {
        float s = 0.f;
        #pragma unroll
        for (int i = 0; i < 8; ++i) s += lacc[i];
        lossp[ci] = s;
        __threadfence();
        int t = atomicAdd(cnt0, 1);
        if (t == TC - 1) {                  // last block: deterministic-order final sum
            __threadfence();
            float tot = 0.f;
            for (int i = 0; i < TC; ++i)
                tot += __hip_atomic_load(lossp + i, __ATOMIC_RELAXED, __HIP_MEMORY_SCOPE_AGENT);
            out[0] = tot * (1.f / (TC * NV));
        }
    }
}

extern "C" void kernel_launch(void* const* d_in, const int* in_sizes, int n_in,
                              void* d_out, int out_size, void* d_ws, size_t ws_size,
                              hipStream_t stream) {
    (void)in_sizes; (void)n_in; (void)out_size; (void)ws_size;
    const float* feats   = (const float*)d_in[0];
    const int*   labels  = (const int*)d_in[1];
    const int*   predict = (const int*)d_in[2];
    const float* prob    = (const float*)d_in[3];
    const float* queue   = (const float*)d_in[4];
    float* ws  = (float*)d_ws;
    float* out = (float*)d_out;

    int*   sel     = (int*)(ws + WS_SEL);
    float* lossp   = ws + WS_LOSSP;
    int*   cnt0    = (int*)(ws + WS_CNT0);
    float* negpart = ws + WS_NEGPART;
    float* anorm   = ws + WS_ANORM;
    float* arows   = ws + WS_AROWS;
    float* part    = ws + WS_PART;
    unsigned char* lab8 = (unsigned char*)(ws + WS_LAB8);

    k_pre    <<<539, 256, 0, stream>>>(labels, predict, prob, lab8, sel, cnt0);
    k_gather <<<TC * NV, 128, 0, stream>>>(feats, sel, arows, anorm);
    k_main   <<<NNEGBLK + NSUMBLK, 256, 0, stream>>>(feats, lab8, queue, arows, anorm, part, negpart);
    k_loss   <<<TC, 256, 0, stream>>>(arows, anorm, part, negpart, lossp, cnt0, out);
}

// Round 9
// 135.148 us; speedup vs baseline: 3.1850x; 3.1850x over previous
//
#include <hip/hip_runtime.h>

#define NUMC 14
#define FD 128
#define SPATIAL (16*128*128)      // 262144 per batch = 2^18
#define N_TOTAL (2*SPATIAL)       // 524288
#define NV 50
#define NH 25
#define TC 13
#define QLEN 4096
#define MCH 64                    // negatives per neg-block
#define NCHUNK 32                 // 2048 / MCH
#define NSTR (FD + 4)             // 132: queue row stride in LDS (words)
#define NNEGBLK (TC * NCHUNK)     // 416
#define THRESH_F 0.3f

// k_sums geometry: 4 channel-planes per thread, register accumulators
#define ITER 8
#define PXBLK (256 * 4 * ITER)    // 8192 pixels per block
#define NQUAD 64                  // 256 planes / 4
#define NCHK (SPATIAL / PXBLK)    // 32 chunks per quad
#define NSUMBLK (NQUAD * NCHK)    // 2048 blocks
#define NPI (NCHK * 4)            // 128 partials per (class,channel)

typedef float f32x4 __attribute__((ext_vector_type(4)));

// ws offsets in 4-byte units (16B-aligned regions)
#define WS_SEL     0              // int[656]
#define WS_LOSSP   656            // float[13]
#define WS_CNT0    672            // int[1] (pad to 680)
#define WS_NEGPART 680            // float[650*32] -> ends 21480
#define WS_ANORM   21480          // float[656] -> ends 22136 (pad 22144)
#define WS_AROWS   22144          // float[650*128] -> ends 105344
#define WS_PART    105344         // float[14*128*128] = 229376 -> ends 334720
#define WS_LAB8    334720         // uchar[524288] = 131072 words -> ends 465792

// ---------------- kernel 1: label prep + anchor select + init ----------------
__global__ __launch_bounds__(256) void k_pre(const int* __restrict__ labels,
        const int* __restrict__ predict, const float* __restrict__ prob,
        unsigned char* __restrict__ lab8, int* __restrict__ sel, int* __restrict__ cnt0) {
    int blk = blockIdx.x;
    int tid = threadIdx.x;
    if (blk < 512) {
        int n = blk * 1024 + tid * 4;
        int4   lb = *(const int4*)(labels + n);
        float4 pv = *(const float4*)(prob + n);
        uchar4 o;
        o.x = pv.x > THRESH_F ? (unsigned char)(lb.x & 15) : (unsigned char)15;
        o.y = pv.y > THRESH_F ? (unsigned char)(lb.y & 15) : (unsigned char)15;
        o.z = pv.z > THRESH_F ? (unsigned char)(lb.z & 15) : (unsigned char)15;
        o.w = pv.w > THRESH_F ? (unsigned char)(lb.w & 15) : (unsigned char)15;
        *(uchar4*)(lab8 + n) = o;
    } else if (blk < 538) {
        if (tid >= 64) return;
        int cat = blk - 512;               // 0..25
        int c = 1 + (cat >> 1);
        bool hard = (cat & 1) == 0;
        int lane = tid;
        int* slot = sel + (c - 1) * NV + (hard ? 0 : NH);
        int found = 0;
        for (int base = 0; base < N_TOTAL && found < NH; base += 64) {
            int n = base + lane;
            bool m = false;
            int pr = predict[n];
            if (pr == c && prob[n] > THRESH_F) {
                int lb = labels[n];
                m = hard ? (lb != c) : (lb == c);
            }
            unsigned long long mask = __ballot(m);
            int rank = __popcll(mask & ((1ull << lane) - 1ull));
            if (m && (found + rank) < NH) slot[found + rank] = n;
            found += __popcll(mask);
        }
        if (lane >= found && lane < NH) slot[lane] = N_TOTAL - 1;  // OOB-gather clamp
    } else {
        if (tid == 0) cnt0[0] = 0;
    }
}

// ---------------- kernel 2: gather anchors (contig arows) + norms ----------------
__global__ __launch_bounds__(128) void k_gather(const float* __restrict__ feats,
        const int* __restrict__ sel, float* __restrict__ arows, float* __restrict__ anorm) {
    __shared__ float red[2];
    int r = blockIdx.x;          // 0..649
    int t = threadIdx.x;         // 0..127 = channel
    int n = sel[r];
    int b = n >> 18, sp = n & (SPATIAL - 1);
    float v = feats[((size_t)(b * FD + t)) * SPATIAL + sp];
    arows[r * FD + t] = v;
    float a = v * v;
    #pragma unroll
    for (int o = 32; o; o >>= 1) a += __shfl_xor(a, o);
    if ((t & 63) == 0) red[t >> 6] = a;
    __syncthreads();
    if (t == 0) anorm[r] = sqrtf(red[0] + red[1]);
}

// ---------------- kernel 3: negatives exp-sum partials ----------------
__global__ __launch_bounds__(256) void k_neg(const float* __restrict__ queue,
        const float* __restrict__ arows, const float* __restrict__ anorm,
        float* __restrict__ negpart) {
    __shared__ float n_s[MCH * NSTR];   // 33 KB
    __shared__ float an_s[NV];
    int tid = threadIdx.x;
    int lane = tid & 63, w = tid >> 6;
    int ci = blockIdx.x >> 5;          // 0..12
    int chunk = blockIdx.x & 31;       // 0..31
    if (tid < NV) an_s[tid] = anorm[ci * NV + tid];
    const float* qp = queue + ((size_t)(ci + 1) * QLEN + (QLEN / 2) + chunk * MCH) * (size_t)FD;
    for (int i = tid; i < MCH * (FD / 4); i += 256) {
        int m = i >> 5, k4 = i & 31;
        ((float4*)(n_s + m * NSTR))[k4] = ((const float4*)qp)[i];
    }
    __syncthreads();
    // per-lane inverse norm of its negative row (row = lane)
    const float4* nrow = (const float4*)(n_s + lane * NSTR);
    float sq = 0.f;
    #pragma unroll
    for (int k = 0; k < FD / 4; ++k) {
        float4 t = nrow[k];
        sq += t.x*t.x + t.y*t.y + t.z*t.z + t.w*t.w;
    }
    float inn = 10.f * rsqrtf(sq);   // 1/TEMP folded in
    float* np = negpart + (size_t)(ci * NV) * NCHUNK + chunk;   // [row][chunk]
    const float4* abase = (const float4*)(arows + (size_t)(ci * NV) * FD);
    for (int v = w; v < NV; v += 4) {
        const float4* a4 = abase + v * (FD / 4);   // wave-uniform -> L1 broadcast
        float dot = 0.f;
        #pragma unroll
        for (int k = 0; k < FD / 4; ++k) {
            float4 x = a4[k], y = nrow[k];
            dot += x.x*y.x + x.y*y.y + x.z*y.z + x.w*y.w;
        }
        float e = __expf(dot * inn / an_s[v]);
        #pragma unroll
        for (int o = 32; o; o >>= 1) e += __shfl_xor(e, o);
        if (lane == 0) np[(size_t)v * NCHUNK] = e;
    }
}

// ---------------- kernel 4: class sums in registers, zero LDS ----------------
__global__ __launch_bounds__(256) void k_sums(const float* __restrict__ feats,
        const unsigned char* __restrict__ lab8, float* __restrict__ part) {
    int tid = threadIdx.x;
    int q     = blockIdx.x >> 5;        // plane-quad 0..63 (planes 4q..4q+3)
    int chunk = blockIdx.x & 31;        // 0..31
    int b = q >> 5;                     // batch
    const float* fp = feats + (size_t)(q * 4) * SPATIAL + chunk * PXBLK;
    const unsigned char* lp = lab8 + (size_t)b * SPATIAL + chunk * PXBLK;

    float acc[NUMC][4];
    #pragma unroll
    for (int c = 0; c < NUMC; ++c)
        #pragma unroll
        for (int j = 0; j < 4; ++j) acc[c][j] = 0.f;

    #pragma unroll 2
    for (int i = 0; i < ITER; ++i) {
        int off = i * 1024 + (tid << 2);
        uchar4 u = *(const uchar4*)(lp + off);
        f32x4 v0 = *(const f32x4*)(fp + off);
        f32x4 v1 = *(const f32x4*)(fp + SPATIAL + off);
        f32x4 v2 = *(const f32x4*)(fp + 2 * SPATIAL + off);
        f32x4 v3 = *(const f32x4*)(fp + 3 * SPATIAL + off);
        #pragma unroll
        for (int c = 0; c < NUMC; ++c) {
            float m0 = (u.x == c) ? 1.f : 0.f;
            float m1 = (u.y == c) ? 1.f : 0.f;
            float m2 = (u.z == c) ? 1.f : 0.f;
            float m3 = (u.w == c) ? 1.f : 0.f;
            acc[c][0] = fmaf(m3, v0.w, fmaf(m2, v0.z, fmaf(m1, v0.y, fmaf(m0, v0.x, acc[c][0]))));
            acc[c][1] = fmaf(m3, v1.w, fmaf(m2, v1.z, fmaf(m1, v1.y, fmaf(m0, v1.x, acc[c][1]))));
            acc[c][2] = fmaf(m3, v2.w, fmaf(m2, v2.z, fmaf(m1, v2.y, fmaf(m0, v2.x, acc[c][2]))));
            acc[c][3] = fmaf(m3, v3.w, fmaf(m2, v3.z, fmaf(m1, v3.y, fmaf(m0, v3.x, acc[c][3]))));
        }
    }

    // wave shuffle-reduce -> per-wave partials, layout part[class][ch][NPI]
    int lane = tid & 63, w = tid >> 6;
    int pi = chunk * 4 + w;             // 0..127
    #pragma unroll
    for (int c = 0; c < NUMC; ++c)
        #pragma unroll
        for (int j = 0; j < 4; ++j) {
            float x = acc[c][j];
            #pragma unroll
            for (int o = 32; o; o >>= 1) x += __shfl_xor(x, o);
            if (lane == 0) {
                int ch = (q & 31) * 4 + j;
                part[((size_t)c * FD + ch) * NPI + pi] = x;
            }
        }
}

// ---------------- kernel 5: per-class loss + deterministic final reduce ----------------
__global__ __launch_bounds__(256) void k_loss(const float* __restrict__ arows,
        const float* __restrict__ anorm, const float* __restrict__ part,
        const float* __restrict__ negpart, float* __restrict__ lossp,
        int* __restrict__ cnt0, float* __restrict__ out) {
    __shared__ float p_s[FD];
    __shared__ float red_s[2];
    __shared__ float lacc[8];
    int tid = threadIdx.x;
    int ci = blockIdx.x, c = ci + 1;
    // class-sum reduce over NPI partials per channel (cnt cancels under l2n)
    if (tid < 128) {
        const float* pp = part + ((size_t)c * FD + tid) * NPI;
        float s = 0.f;
        #pragma unroll 8
        for (int k = 0; k < NPI; ++k) s += pp[k];
        p_s[tid] = s;
    }
    __syncthreads();
    if (tid < 128) {
        float q = p_s[tid] * p_s[tid];
        #pragma unroll
        for (int o = 32; o; o >>= 1) q += __shfl_xor(q, o);
        if ((tid & 63) == 0) red_s[tid >> 6] = q;
    }
    __syncthreads();
    float pninv10 = 10.f * rsqrtf(red_s[0] + red_s[1]);   // 1/(||psum|| * TEMP)
    int grp = tid >> 5, l32 = tid & 31;
    float acc = 0.f;
    for (int r = grp; r < NV; r += 8) {
        int ar = ci * NV + r;
        const float4* a4 = (const float4*)(arows + (size_t)ar * FD);
        const float4* p4 = (const float4*)p_s;
        float4 x = a4[l32], y = p4[l32];
        float d = x.x*y.x + x.y*y.y + x.z*y.z + x.w*y.w;
        float ns = negpart[(size_t)ar * NCHUNK + l32];
        #pragma unroll
        for (int o = 16; o; o >>= 1) { d += __shfl_xor(d, o); ns += __shfl_xor(ns, o); }
        if (l32 == 0) {
            float logit = d * pninv10 / anorm[ar];
            acc += -logit + logf(__expf(logit) + ns);
        }
    }
    if (l32 == 0) lacc[grp] = acc;
    __syncthreads();
    if (tid == 0) {
        float s = 0.f;
        #pragma unroll
        for (int i = 0; i < 8; ++i) s += lacc[i];
        lossp[ci] = s;
        __threadfence();
        int t = atomicAdd(cnt0, 1);
        if (t == TC - 1) {                  // last block: deterministic-order final sum
            __threadfence();
            float tot = 0.f;
            for (int i = 0; i < TC; ++i)
                tot += __hip_atomic_load(lossp + i, __ATOMIC_RELAXED, __HIP_MEMORY_SCOPE_AGENT);
            out[0] = tot * (1.f / (TC * NV));
        }
    }
}

extern "C" void kernel_launch(void* const* d_in, const int* in_sizes, int n_in,
                              void* d_out, int out_size, void* d_ws, size_t ws_size,
                              hipStream_t stream) {
    (void)in_sizes; (void)n_in; (void)out_size; (void)ws_size;
    const float* feats   = (const float*)d_in[0];
    const int*   labels  = (const int*)d_in[1];
    const int*   predict = (const int*)d_in[2];
    const float* prob    = (const float*)d_in[3];
    const float* queue   = (const float*)d_in[4];
    float* ws  = (float*)d_ws;
    float* out = (float*)d_out;

    int*   sel     = (int*)(ws + WS_SEL);
    float* lossp   = ws + WS_LOSSP;
    int*   cnt0    = (int*)(ws + WS_CNT0);
    float* negpart = ws + WS_NEGPART;
    float* anorm   = ws + WS_ANORM;
    float* arows   = ws + WS_AROWS;
    float* part    = ws + WS_PART;
    unsigned char* lab8 = (unsigned char*)(ws + WS_LAB8);

    k_pre    <<<539, 256, 0, stream>>>(labels, predict, prob, lab8, sel, cnt0);
    k_gather <<<TC * NV, 128, 0, stream>>>(feats, sel, arows, anorm);
    k_neg    <<<NNEGBLK, 256, 0, stream>>>(queue, arows, anorm, negpart);
    k_sums   <<<NSUMBLK, 256, 0, stream>>>(feats, lab8, part);
    k_loss   <<<TC, 256, 0, stream>>>(arows, anorm, part, negpart, lossp, cnt0, out);
}

// Round 10
// 100.295 us; speedup vs baseline: 4.2918x; 1.3475x over previous
//
#include <hip/hip_runtime.h>

#define NUMC 14
#define FD 128
#define SPATIAL (16*128*128)      // 262144 per batch = 2^18
#define N_TOTAL (2*SPATIAL)       // 524288
#define NV 50
#define NH 25
#define TC 13
#define QLEN 4096
#define MCH 64                    // negatives per neg-block
#define NCHUNK 32                 // 2048 / MCH
#define NSTR (FD + 4)             // 132: queue row stride in LDS (words)
#define NNEGBLK (TC * NCHUNK)     // 416
#define THRESH_F 0.3f

// k_sums geometry: one plane-chunk per block, private LDS rows
#define RSTR 17                   // per-thread region: 16 slots + 1 pad (17.4 KB/block)
#define PXB 32768                 // pixels per block
#define CHB (SPATIAL / PXB)       // 8 chunks per plane
#define NSUMBLK (256 * CHB)       // 2048 blocks
#define NPI 64                    // partials per (class,channel): 2 batches*8 chunks*4 waves

typedef float f32x4 __attribute__((ext_vector_type(4)));

// ws offsets in 4-byte units (16B-aligned regions)
#define WS_SEL     0              // int[656]
#define WS_LOSSP   656            // float[13]
#define WS_CNT0    672            // int[1] (pad to 680)
#define WS_NEGPART 680            // float[650*32] -> ends 21480
#define WS_ANORM   21480          // float[656] -> ends 22136 (pad 22144)
#define WS_AROWS   22144          // float[650*128] -> ends 105344
#define WS_PART    105344         // float[14*128*64] = 114688 -> ends 220032
#define WS_LAB8    220032         // uchar[524288] = 131072 words -> ends 351104

// ---------------- kernel 1: label prep + windowed anchor select + init ----------------
__global__ __launch_bounds__(256) void k_pre(const int* __restrict__ labels,
        const int* __restrict__ predict, const float* __restrict__ prob,
        unsigned char* __restrict__ lab8, int* __restrict__ sel, int* __restrict__ cnt0) {
    int blk = blockIdx.x;
    int tid = threadIdx.x;
    if (blk < 512) {
        int n = blk * 1024 + tid * 4;
        int4   lb = *(const int4*)(labels + n);
        float4 pv = *(const float4*)(prob + n);
        uchar4 o;
        o.x = pv.x > THRESH_F ? (unsigned char)(lb.x & 15) : (unsigned char)15;
        o.y = pv.y > THRESH_F ? (unsigned char)(lb.y & 15) : (unsigned char)15;
        o.z = pv.z > THRESH_F ? (unsigned char)(lb.z & 15) : (unsigned char)15;
        o.w = pv.w > THRESH_F ? (unsigned char)(lb.w & 15) : (unsigned char)15;
        *(uchar4*)(lab8 + n) = o;
    } else if (blk < 538) {
        // windowed select: 256 pixels/window, 4 waves cooperate via ballot+LDS rank
        __shared__ unsigned long long masks[4];
        int cat = blk - 512;               // 0..25
        int c = 1 + (cat >> 1);
        bool hard = (cat & 1) == 0;
        int lane = tid & 63, w = tid >> 6;
        int* slot = sel + (c - 1) * NV + (hard ? 0 : NH);
        int found = 0;
        for (int base = 0; base < N_TOTAL && found < NH; base += 256) {
            int n = base + tid;
            int pr = predict[n];
            int lb = labels[n];
            float pb = prob[n];
            bool m = (pr == c) && (pb > THRESH_F) && (hard ? (lb != c) : (lb == c));
            unsigned long long mk = __ballot(m);
            if (lane == 0) masks[w] = mk;
            __syncthreads();
            int pre = 0;
            #pragma unroll
            for (int j = 0; j < 4; ++j) {
                unsigned long long mj = masks[j];
                if (j < w) pre += __popcll(mj);
            }
            int rank = found + pre + __popcll(mk & ((1ull << lane) - 1ull));
            if (m && rank < NH) slot[rank] = n;
            found += __popcll(masks[0]) + __popcll(masks[1])
                   + __popcll(masks[2]) + __popcll(masks[3]);
            __syncthreads();
        }
        if (tid < NH && tid >= found) slot[tid] = N_TOTAL - 1;  // OOB-gather clamp
    } else {
        if (tid == 0) cnt0[0] = 0;
    }
}

// ---------------- kernel 2: gather anchors (contig arows) + norms ----------------
__global__ __launch_bounds__(128) void k_gather(const float* __restrict__ feats,
        const int* __restrict__ sel, float* __restrict__ arows, float* __restrict__ anorm) {
    __shared__ float red[2];
    int r = blockIdx.x;          // 0..649
    int t = threadIdx.x;         // 0..127 = channel
    int n = sel[r];
    int b = n >> 18, sp = n & (SPATIAL - 1);
    float v = feats[((size_t)(b * FD + t)) * SPATIAL + sp];
    arows[r * FD + t] = v;
    float a = v * v;
    #pragma unroll
    for (int o = 32; o; o >>= 1) a += __shfl_xor(a, o);
    if ((t & 63) == 0) red[t >> 6] = a;
    __syncthreads();
    if (t == 0) anorm[r] = sqrtf(red[0] + red[1]);
}

// ---------------- kernel 3: negatives exp-sum partials ----------------
__global__ __launch_bounds__(256) void k_neg(const float* __restrict__ queue,
        const float* __restrict__ arows, const float* __restrict__ anorm,
        float* __restrict__ negpart) {
    __shared__ float n_s[MCH * NSTR];   // 33 KB
    __shared__ float an_s[NV];
    int tid = threadIdx.x;
    int lane = tid & 63, w = tid >> 6;
    int ci = blockIdx.x >> 5;          // 0..12
    int chunk = blockIdx.x & 31;       // 0..31
    if (tid < NV) an_s[tid] = anorm[ci * NV + tid];
    const float* qp = queue + ((size_t)(ci + 1) * QLEN + (QLEN / 2) + chunk * MCH) * (size_t)FD;
    for (int i = tid; i < MCH * (FD / 4); i += 256) {
        int m = i >> 5, k4 = i & 31;
        ((float4*)(n_s + m * NSTR))[k4] = ((const float4*)qp)[i];
    }
    __syncthreads();
    const float4* nrow = (const float4*)(n_s + lane * NSTR);
    float sq = 0.f;
    #pragma unroll
    for (int k = 0; k < FD / 4; ++k) {
        float4 t = nrow[k];
        sq += t.x*t.x + t.y*t.y + t.z*t.z + t.w*t.w;
    }
    float inn = 10.f * rsqrtf(sq);   // 1/TEMP folded in
    float* np = negpart + (size_t)(ci * NV) * NCHUNK + chunk;   // [row][chunk]
    const float4* abase = (const float4*)(arows + (size_t)(ci * NV) * FD);
    for (int v = w; v < NV; v += 4) {
        const float4* a4 = abase + v * (FD / 4);   // wave-uniform -> L1 broadcast
        float dot = 0.f;
        #pragma unroll
        for (int k = 0; k < FD / 4; ++k) {
            float4 x = a4[k], y = nrow[k];
            dot += x.x*y.x + x.y*y.y + x.z*y.z + x.w*y.w;
        }
        float e = __expf(dot * inn / an_s[v]);
        #pragma unroll
        for (int o = 32; o; o >>= 1) e += __shfl_xor(e, o);
        if (lane == 0) np[(size_t)v * NCHUNK] = e;
    }
}

// ---------------- kernel 4: class sums, 17.4KB private LDS rows, no barriers ----------------
__global__ __launch_bounds__(256) void k_sums(const float* __restrict__ feats,
        const unsigned char* __restrict__ lab8, float* __restrict__ part) {
    __shared__ float smem[256 * RSTR];   // 17.4 KB -> 8 blocks/CU
    int tid = threadIdx.x;
    int plane = blockIdx.x >> 3;        // 0..255 = b*128 + ch
    int chunk = blockIdx.x & (CHB - 1); // 0..7
    int b = plane >> 7;
    int ch = plane & 127;
    int r0 = tid * RSTR;
    #pragma unroll
    for (int k = 0; k < RSTR; ++k) smem[r0 + k] = 0.f;   // own region only

    const f32x4*  fp4 = (const f32x4*)(feats + (size_t)plane * SPATIAL) + (chunk << 13);
    const uchar4* lp4 = (const uchar4*)(lab8 + (size_t)b * SPATIAL) + (chunk << 13);
    f32x4  v = fp4[tid];
    uchar4 u = lp4[tid];
    for (int i = 0; i < 31; ++i) {
        f32x4  vn = fp4[(i + 1) * 256 + tid];
        uchar4 un = lp4[(i + 1) * 256 + tid];
        smem[r0 + (u.x & 15)] += v.x;
        smem[r0 + (u.y & 15)] += v.y;
        smem[r0 + (u.z & 15)] += v.z;
        smem[r0 + (u.w & 15)] += v.w;
        v = vn; u = un;
    }
    smem[r0 + (u.x & 15)] += v.x;
    smem[r0 + (u.y & 15)] += v.y;
    smem[r0 + (u.z & 15)] += v.z;
    smem[r0 + (u.w & 15)] += v.w;

    // shuffle-only epilogue: reduce each class across the wave, write per-wave partial
    int lane = tid & 63, w = tid >> 6;
    int pi = b * 32 + chunk * 4 + w;    // 0..63
    #pragma unroll
    for (int c = 0; c < NUMC; ++c) {
        float x = smem[r0 + c];
        #pragma unroll
        for (int o = 32; o; o >>= 1) x += __shfl_xor(x, o);
        if (lane == 0) part[((size_t)c * FD + ch) * NPI + pi] = x;
    }
}

// ---------------- kernel 5: per-class loss + deterministic final reduce ----------------
__global__ __launch_bounds__(256) void k_loss(const float* __restrict__ arows,
        const float* __restrict__ anorm, const float* __restrict__ part,
        const float* __restrict__ negpart, float* __restrict__ lossp,
        int* __restrict__ cnt0, float* __restrict__ out) {
    __shared__ float p_s[FD];
    __shared__ float red_s[2];
    __shared__ float lacc[8];
    int tid = threadIdx.x;
    int ci = blockIdx.x, c = ci + 1;
    // class-sum reduce over NPI partials per channel (cnt cancels under l2n)
    if (tid < 128) {
        const float* pp = part + ((size_t)c * FD + tid) * NPI;
        float s = 0.f;
        #pragma unroll 8
        for (int k = 0; k < NPI; ++k) s += pp[k];
        p_s[tid] = s;
    }
    __syncthreads();
    if (tid < 128) {
        float q = p_s[tid] * p_s[tid];
        #pragma unroll
        for (int o = 32; o; o >>= 1) q += __shfl_xor(q, o);
        if ((tid & 63) == 0) red_s[tid >> 6] = q;
    }
    __syncthreads();
    float pninv10 = 10.f * rsqrtf(red_s[0] + red_s[1]);   // 1/(||psum|| * TEMP)
    int grp = tid >> 5, l32 = tid & 31;
    float acc = 0.f;
    for (int r = grp; r < NV; r += 8) {
        int ar = ci * NV + r;
        const float4* a4 = (const float4*)(arows + (size_t)ar * FD);
        const float4* p4 = (const float4*)p_s;
        float4 x = a4[l32], y = p4[l32];
        float d = x.x*y.x + x.y*y.y + x.z*y.z + x.w*y.w;
        float ns = negpart[(size_t)ar * NCHUNK + l32];
        #pragma unroll
        for (int o = 16; o; o >>= 1) { d += __shfl_xor(d, o); ns += __shfl_xor(ns, o); }
        if (l32 == 0) {
            float logit = d * pninv10 / anorm[ar];
            acc += -logit + logf(__expf(logit) + ns);
        }
    }
    if (l32 == 0) lacc[grp] = acc;
    __syncthreads();
    if (tid == 0) {
        float s = 0.f;
        #pragma unroll
        for (int i = 0; i < 8; ++i) s += lacc[i];
        lossp[ci] = s;
        __threadfence();
        int t = atomicAdd(cnt0, 1);
        if (t == TC - 1) {                  // last block: deterministic-order final sum
            __threadfence();
            float tot = 0.f;
            for (int i = 0; i < TC; ++i)
                tot += __hip_atomic_load(lossp + i, __ATOMIC_RELAXED, __HIP_MEMORY_SCOPE_AGENT);
            out[0] = tot * (1.f / (TC * NV));
        }
    }
}

extern "C" void kernel_launch(void* const* d_in, const int* in_sizes, int n_in,
                              void* d_out, int out_size, void* d_ws, size_t ws_size,
                              hipStream_t stream) {
    (void)in_sizes; (void)n_in; (void)out_size; (void)ws_size;
    const float* feats   = (const float*)d_in[0];
    const int*   labels  = (const int*)d_in[1];
    const int*   predict = (const int*)d_in[2];
    const float* prob    = (const float*)d_in[3];
    const float* queue   = (const float*)d_in[4];
    float* ws  = (float*)d_ws;
    float* out = (float*)d_out;

    int*   sel     = (int*)(ws + WS_SEL);
    float* lossp   = ws + WS_LOSSP;
    int*   cnt0    = (int*)(ws + WS_CNT0);
    float* negpart = ws + WS_NEGPART;
    float* anorm   = ws + WS_ANORM;
    float* arows   = ws + WS_AROWS;
    float* part    = ws + WS_PART;
    unsigned char* lab8 = (unsigned char*)(ws + WS_LAB8);

    k_pre    <<<539, 256, 0, stream>>>(labels, predict, prob, lab8, sel, cnt0);
    k_gather <<<TC * NV, 128, 0, stream>>>(feats, sel, arows, anorm);
    k_neg    <<<NNEGBLK, 256, 0, stream>>>(queue, arows, anorm, negpart);
    k_sums   <<<NSUMBLK, 256, 0, stream>>>(feats, lab8, part);
    k_loss   <<<TC, 256, 0, stream>>>(arows, anorm, part, negpart, lossp, cnt0, out);
}